// Round 1
// baseline (1316.899 us; speedup 1.0000x reference)
//
#include <hip/hip_runtime.h>
#include <math.h>

#define Bc 4
#define Nc_ 4096
#define DINc 768
#define Dc 256
#define Sc 8
#define SIGMAc 5.0f
#define SCALEc 0.0625f
#define EPSc 1e-8f

// ---------------- fp32 tiled GEMM, optional fused LayerNorm on A-load, optional ReLU ----
template<bool LNA, bool RELU>
__global__ __launch_bounds__(256) void gemm_k(
    const float* __restrict__ A, const float* __restrict__ Wt,
    const float* __restrict__ bias, float* __restrict__ C,
    int M, int Ncols, int K,
    const float* __restrict__ stats,
    const float* __restrict__ lng, const float* __restrict__ lnb)
{
    __shared__ float As[16][68];
    __shared__ float Ws[16][68];
    const int tid = threadIdx.x;
    const int tx = tid & 15, ty = tid >> 4;
    const int m0 = blockIdx.y * 64, n0 = blockIdx.x * 64;
    const int arow = tid >> 2;
    const int akq = (tid & 3) * 4;
    float acc[4][4] = {};
    float meanr = 0.f, rstdr = 0.f;
    if (LNA) { meanr = stats[(m0 + arow) * 2]; rstdr = stats[(m0 + arow) * 2 + 1]; }
    const float* aptr = A + (size_t)(m0 + arow) * K + akq;
    for (int k0 = 0; k0 < K; k0 += 16) {
        float4 av = *reinterpret_cast<const float4*>(aptr + k0);
        float a4[4] = {av.x, av.y, av.z, av.w};
        #pragma unroll
        for (int i = 0; i < 4; i++) {
            float v = a4[i];
            if (LNA) {
                int kk = k0 + akq + i;
                v = (v - meanr) * rstdr * lng[kk] + lnb[kk];
            }
            As[akq + i][arow] = v;
        }
        {
            const int col = tid & 63;
            const int kr0 = tid >> 6;
            #pragma unroll
            for (int r = 0; r < 4; r++) {
                int kk = kr0 + r * 4;
                Ws[kk][col] = Wt[(size_t)(k0 + kk) * Ncols + n0 + col];
            }
        }
        __syncthreads();
        #pragma unroll
        for (int k = 0; k < 16; k++) {
            float4 a4v = *reinterpret_cast<const float4*>(&As[k][ty * 4]);
            float4 b4v = *reinterpret_cast<const float4*>(&Ws[k][tx * 4]);
            float aa[4] = {a4v.x, a4v.y, a4v.z, a4v.w};
            float bb[4] = {b4v.x, b4v.y, b4v.z, b4v.w};
            #pragma unroll
            for (int i = 0; i < 4; i++)
                #pragma unroll
                for (int j = 0; j < 4; j++)
                    acc[i][j] += aa[i] * bb[j];
        }
        __syncthreads();
    }
    #pragma unroll
    for (int i = 0; i < 4; i++) {
        int row = m0 + ty * 4 + i;
        #pragma unroll
        for (int j = 0; j < 4; j++) {
            int col = n0 + tx * 4 + j;
            float v = acc[i][j] + bias[col];
            if (RELU) v = fmaxf(v, 0.f);
            C[(size_t)row * Ncols + col] = v;
        }
    }
}

// ---------------- per-row LayerNorm stats (mean, rstd), one wave per row ----------------
__global__ __launch_bounds__(256) void ln_stats_k(const float* __restrict__ X,
                                                  float* __restrict__ st, int K)
{
    int wave = threadIdx.x >> 6, lane = threadIdx.x & 63;
    int row = blockIdx.x * 4 + wave;
    const float* x = X + (size_t)row * K;
    float s = 0.f, s2 = 0.f;
    for (int k = lane; k < K; k += 64) { float v = x[k]; s += v; s2 += v * v; }
    #pragma unroll
    for (int off = 32; off > 0; off >>= 1) { s += __shfl_xor(s, off); s2 += __shfl_xor(s2, off); }
    if (lane == 0) {
        float mean = s / K;
        float var = s2 / K - mean * mean;
        st[row * 2] = mean;
        st[row * 2 + 1] = rsqrtf(var + 1e-5f);
    }
}

// ---------------- KVF = [Kw@fw1 | Vw@fw1]  (256 x 512) ----------------
__global__ void kvf_k(const float* __restrict__ Kw, const float* __restrict__ Vw,
                      const float* __restrict__ fw1, float* __restrict__ KVF)
{
    int k = blockIdx.x;      // 0..255
    int j = threadIdx.x;     // 0..511
    const float* Mrow = (j < 256 ? Kw : Vw) + k * 256;
    int jj = j & 255;
    float acc = 0.f;
    for (int d = 0; d < 256; d++) acc += Mrow[d] * fw1[d * 256 + jj];
    KVF[k * 512 + j] = acc;
}

// ---------------- G3 = gw@fw1 (3x256), bias2 = [gb@fw1+fb1 | gb@fw1+fb1] (512) ----------
__global__ void g3b_k(const float* __restrict__ gw, const float* __restrict__ gb,
                      const float* __restrict__ fb1, const float* __restrict__ fw1,
                      float* __restrict__ G3, float* __restrict__ bias2)
{
    int j = threadIdx.x; // 0..255
    float g0 = 0, g1 = 0, g2 = 0, bb = 0;
    for (int d = 0; d < 256; d++) {
        float f = fw1[d * 256 + j];
        g0 += gw[d] * f;
        g1 += gw[256 + d] * f;
        g2 += gw[512 + d] * f;
        bb += gb[d] * f;
    }
    G3[j] = g0; G3[256 + j] = g1; G3[512 + j] = g2;
    float b1v = fb1[j] + bb;
    bias2[j] = b1v; bias2[256 + j] = b1v;
}

// ---------------- init slots / S_p / S_s state ----------------
__global__ void init_k(const float* __restrict__ slots_param, const float* __restrict__ Sp0,
                       const float* __restrict__ Ss0, float* __restrict__ slots,
                       float* __restrict__ Spb, float* __restrict__ Ssb)
{
    int idx = blockIdx.x * 256 + threadIdx.x; // 0..8191
    slots[idx] = slots_param[idx & 2047];
    if (idx < Bc * Sc * 3) {
        int s3 = idx % 24;
        Spb[idx] = Sp0[s3];
        Ssb[idx] = Ss0[s3];
    }
}

// ---------------- per-(b,s): q = LN(slots)@Qw ; w2q = fw2@q ; qc = q.fb2 ; inv ----------
__global__ __launch_bounds__(256) void qprep_k(
    const float* __restrict__ slots, const float* __restrict__ norm_g, const float* __restrict__ norm_b,
    const float* __restrict__ Qw, const float* __restrict__ fw2, const float* __restrict__ fb2,
    const float* __restrict__ Ssb, float* __restrict__ w2q, float* __restrict__ qc,
    float* __restrict__ invv)
{
    int bs = blockIdx.x;
    int tid = threadIdx.x;
    int lane = tid & 63, wave = tid >> 6;
    __shared__ float sl[256], q[256];
    __shared__ float redS[4], redS2[4];
    float v = slots[bs * 256 + tid];
    float s = v, s2 = v * v;
    #pragma unroll
    for (int off = 32; off > 0; off >>= 1) { s += __shfl_xor(s, off); s2 += __shfl_xor(s2, off); }
    if (lane == 0) { redS[wave] = s; redS2[wave] = s2; }
    __syncthreads();
    float mean = (redS[0] + redS[1] + redS[2] + redS[3]) * (1.f / 256.f);
    float m2 = (redS2[0] + redS2[1] + redS2[2] + redS2[3]) * (1.f / 256.f);
    float rstd = rsqrtf(m2 - mean * mean + 1e-5f);
    sl[tid] = (v - mean) * rstd * norm_g[tid] + norm_b[tid];
    __syncthreads();
    float qa = 0.f;
    for (int i = 0; i < 256; i++) qa += sl[i] * Qw[i * 256 + tid];
    q[tid] = qa;
    __syncthreads();
    float wq = 0.f;
    for (int d = 0; d < 256; d++) wq += fw2[tid * 256 + d] * q[d];
    w2q[bs * 256 + tid] = wq;
    // qc = sum q[d]*fb2[d]
    float c = qa * fb2[tid];
    #pragma unroll
    for (int off = 32; off > 0; off >>= 1) c += __shfl_xor(c, off);
    __syncthreads();
    if (lane == 0) redS[wave] = c;
    __syncthreads();
    if (tid == 0) qc[bs] = redS[0] + redS[1] + redS[2] + redS[3];
    if (tid < 3) invv[bs * 3 + tid] = 1.f / (Ssb[bs * 3 + tid] * SIGMAc + EPSc);
}

// ---------------- phase A: dots[b,s,n] = (relu(AK + rel@G3) . w2q + qc) * SCALE --------
__global__ __launch_bounds__(256) void phaseA_k(
    const float* __restrict__ AKV, const float* __restrict__ P,
    const float* __restrict__ G3, const float* __restrict__ w2q,
    const float* __restrict__ qc, const float* __restrict__ Spb, const float* __restrict__ invv,
    float* __restrict__ dots)
{
    int b = blockIdx.y;
    int tid = threadIdx.x, wave = tid >> 6, lane = tid & 63;
    const float4* G3f = (const float4*)G3;
    float4 g0 = G3f[lane], g1 = G3f[64 + lane], g2 = G3f[128 + lane];
    float4 wqr[8];
    float sp[8][3], iv[8][3], qcr[8];
    #pragma unroll
    for (int s = 0; s < 8; s++) {
        wqr[s] = ((const float4*)w2q)[(b * 8 + s) * 64 + lane];
        sp[s][0] = Spb[(b * 8 + s) * 3 + 0];
        sp[s][1] = Spb[(b * 8 + s) * 3 + 1];
        sp[s][2] = Spb[(b * 8 + s) * 3 + 2];
        iv[s][0] = invv[(b * 8 + s) * 3 + 0];
        iv[s][1] = invv[(b * 8 + s) * 3 + 1];
        iv[s][2] = invv[(b * 8 + s) * 3 + 2];
        qcr[s] = qc[b * 8 + s];
    }
    for (int i = 0; i < 16; i++) {
        int n = blockIdx.x * 64 + wave * 16 + i;
        size_t base = (size_t)(b * Nc_ + n);
        float4 ak = ((const float4*)(AKV + base * 512))[lane];
        const float* pp = P + base * 3;
        float p0 = pp[0], p1 = pp[1], p2 = pp[2];
        #pragma unroll
        for (int s = 0; s < 8; s++) {
            float r0 = (p0 - sp[s][0]) * iv[s][0];
            float r1 = (p1 - sp[s][1]) * iv[s][1];
            float r2 = (p2 - sp[s][2]) * iv[s][2];
            float h, acc;
            h = fmaxf(ak.x + r0 * g0.x + r1 * g1.x + r2 * g2.x, 0.f); acc  = h * wqr[s].x;
            h = fmaxf(ak.y + r0 * g0.y + r1 * g1.y + r2 * g2.y, 0.f); acc += h * wqr[s].y;
            h = fmaxf(ak.z + r0 * g0.z + r1 * g1.z + r2 * g2.z, 0.f); acc += h * wqr[s].z;
            h = fmaxf(ak.w + r0 * g0.w + r1 * g1.w + r2 * g2.w, 0.f); acc += h * wqr[s].w;
            #pragma unroll
            for (int off = 32; off > 0; off >>= 1) acc += __shfl_xor(acc, off);
            if (lane == 0) dots[(size_t)(b * 8 + s) * Nc_ + n] = (acc + qcr[s]) * SCALEc;
        }
    }
}

// ---------------- softmax over slots + EPS; per-(b,s) partial sums over n ---------------
__global__ __launch_bounds__(256) void softmax_k(
    const float* __restrict__ dots, float* __restrict__ attn_raw, float* __restrict__ denom)
{
    int b = blockIdx.y;
    int n = blockIdx.x * 256 + threadIdx.x;
    float d_[8];
    #pragma unroll
    for (int s = 0; s < 8; s++) d_[s] = dots[(size_t)(b * 8 + s) * Nc_ + n];
    float mx = d_[0];
    #pragma unroll
    for (int s = 1; s < 8; s++) mx = fmaxf(mx, d_[s]);
    float sum = 0.f;
    #pragma unroll
    for (int s = 0; s < 8; s++) { d_[s] = expf(d_[s] - mx); sum += d_[s]; }
    float inv = 1.f / sum;
    float part[8];
    #pragma unroll
    for (int s = 0; s < 8; s++) {
        float a = d_[s] * inv + EPSc;
        attn_raw[(size_t)(b * 8 + s) * Nc_ + n] = a;
        part[s] = a;
    }
    int lane = threadIdx.x & 63, wave = threadIdx.x >> 6;
    __shared__ float red[4][8];
    #pragma unroll
    for (int s = 0; s < 8; s++) {
        float v = part[s];
        #pragma unroll
        for (int off = 32; off > 0; off >>= 1) v += __shfl_xor(v, off);
        if (lane == 0) red[wave][s] = v;
    }
    __syncthreads();
    if (threadIdx.x < 8) {
        int s = threadIdx.x;
        atomicAdd(&denom[b * 8 + s], red[0][s] + red[1][s] + red[2][s] + red[3][s]);
    }
}

// ---------------- phase B: u1 += attn*relu(AV+rel@G3); Sp/Ep2 moments -------------------
__global__ __launch_bounds__(256) void phaseB_k(
    const float* __restrict__ AKV, const float* __restrict__ P,
    const float* __restrict__ G3, const float* __restrict__ attn_raw,
    const float* __restrict__ denom, const float* __restrict__ Spb, const float* __restrict__ invv,
    float* __restrict__ u1acc, float* __restrict__ Spacc, float* __restrict__ Epacc)
{
    int b = blockIdx.y;
    int tid = threadIdx.x, wave = tid >> 6, lane = tid & 63;
    __shared__ float uls[4][2048];
    __shared__ float spls[4][8][6];
    const float4* G3f = (const float4*)G3;
    float4 g0 = G3f[lane], g1 = G3f[64 + lane], g2 = G3f[128 + lane];
    float sp[8][3], iv[8][3], idn[8];
    #pragma unroll
    for (int s = 0; s < 8; s++) {
        sp[s][0] = Spb[(b * 8 + s) * 3 + 0];
        sp[s][1] = Spb[(b * 8 + s) * 3 + 1];
        sp[s][2] = Spb[(b * 8 + s) * 3 + 2];
        iv[s][0] = invv[(b * 8 + s) * 3 + 0];
        iv[s][1] = invv[(b * 8 + s) * 3 + 1];
        iv[s][2] = invv[(b * 8 + s) * 3 + 2];
        idn[s] = 1.f / denom[b * 8 + s];
    }
    float au[8][4] = {};
    float asp[3] = {0, 0, 0}, aep[3] = {0, 0, 0};
    for (int i = 0; i < 16; i++) {
        int n = blockIdx.x * 64 + wave * 16 + i;
        size_t base = (size_t)(b * Nc_ + n);
        float4 av = ((const float4*)(AKV + base * 512 + 256))[lane];
        const float* pp = P + base * 3;
        float p0 = pp[0], p1 = pp[1], p2 = pp[2];
        #pragma unroll
        for (int s = 0; s < 8; s++) {
            float a = attn_raw[(size_t)(b * 8 + s) * Nc_ + n] * idn[s];
            float r0 = (p0 - sp[s][0]) * iv[s][0];
            float r1 = (p1 - sp[s][1]) * iv[s][1];
            float r2 = (p2 - sp[s][2]) * iv[s][2];
            float h;
            h = fmaxf(av.x + r0 * g0.x + r1 * g1.x + r2 * g2.x, 0.f); au[s][0] += a * h;
            h = fmaxf(av.y + r0 * g0.y + r1 * g1.y + r2 * g2.y, 0.f); au[s][1] += a * h;
            h = fmaxf(av.z + r0 * g0.z + r1 * g1.z + r2 * g2.z, 0.f); au[s][2] += a * h;
            h = fmaxf(av.w + r0 * g0.w + r1 * g1.w + r2 * g2.w, 0.f); au[s][3] += a * h;
            if (lane == s) {
                asp[0] += a * p0; asp[1] += a * p1; asp[2] += a * p2;
                aep[0] += a * p0 * p0; aep[1] += a * p1 * p1; aep[2] += a * p2 * p2;
            }
        }
    }
    #pragma unroll
    for (int s = 0; s < 8; s++)
        #pragma unroll
        for (int j = 0; j < 4; j++)
            uls[wave][s * 256 + 4 * lane + j] = au[s][j];
    if (lane < 8) {
        #pragma unroll
        for (int i = 0; i < 3; i++) {
            spls[wave][lane][i] = asp[i];
            spls[wave][lane][3 + i] = aep[i];
        }
    }
    __syncthreads();
    for (int idx = tid; idx < 2048; idx += 256) {
        float v = uls[0][idx] + uls[1][idx] + uls[2][idx] + uls[3][idx];
        atomicAdd(&u1acc[b * 2048 + idx], v);
    }
    if (tid < 48) {
        int s = tid / 6, i = tid % 6;
        float v = spls[0][s][i] + spls[1][s][i] + spls[2][s][i] + spls[3][s][i];
        if (i < 3) atomicAdd(&Spacc[b * 24 + s * 3 + i], v);
        else       atomicAdd(&Epacc[b * 24 + s * 3 + (i - 3)], v);
    }
}

// ---------------- finalize: updates=u1@fw2+fb2 ; S_p,S_s ; GRU ; LN ; MLP ; slots ------
__global__ __launch_bounds__(256) void gru_k(
    const float* __restrict__ u1acc, const float* __restrict__ fw2, const float* __restrict__ fb2,
    const float* __restrict__ Spacc, const float* __restrict__ Epacc,
    const float* __restrict__ gru_wi, const float* __restrict__ gru_wh,
    const float* __restrict__ gru_bi, const float* __restrict__ gru_bh,
    const float* __restrict__ mlp_ln_g, const float* __restrict__ mlp_ln_b,
    const float* __restrict__ mlp_w1, const float* __restrict__ mlp_b1,
    const float* __restrict__ mlp_w2, const float* __restrict__ mlp_b2,
    float* __restrict__ slots, float* __restrict__ Spb, float* __restrict__ Ssb)
{
    int bs = blockIdx.x;
    int tid = threadIdx.x;
    int lane = tid & 63, wave = tid >> 6;
    __shared__ float u1[256], upd[256], y0[256], t1[1024], sprev[256];
    __shared__ float redS[4], redS2[4];
    u1[tid] = u1acc[bs * 256 + tid];
    sprev[tid] = slots[bs * 256 + tid];
    if (tid < 3) {
        float spv = Spacc[bs * 3 + tid];
        float ep = Epacc[bs * 3 + tid];
        Spb[bs * 3 + tid] = spv;
        Ssb[bs * 3 + tid] = sqrtf(fmaxf(ep - spv * spv, 0.f) + EPSc);
    }
    __syncthreads();
    float acc = fb2[tid];
    for (int j = 0; j < 256; j++) acc += u1[j] * fw2[j * 256 + tid];
    upd[tid] = acc;
    __syncthreads();
    float gx0 = gru_bi[tid], gx1 = gru_bi[tid + 256], gx2 = gru_bi[tid + 512];
    float gh0 = gru_bh[tid], gh1 = gru_bh[tid + 256], gh2 = gru_bh[tid + 512];
    for (int d = 0; d < 256; d++) {
        float u = upd[d], spv = sprev[d];
        const float* wi = gru_wi + (size_t)d * 768;
        const float* wh = gru_wh + (size_t)d * 768;
        gx0 += u * wi[tid]; gx1 += u * wi[tid + 256]; gx2 += u * wi[tid + 512];
        gh0 += spv * wh[tid]; gh1 += spv * wh[tid + 256]; gh2 += spv * wh[tid + 512];
    }
    float r = 1.f / (1.f + expf(-(gx0 + gh0)));
    float z = 1.f / (1.f + expf(-(gx1 + gh1)));
    float nn = tanhf(gx2 + r * gh2);
    float h = (1.f - z) * nn + z * sprev[tid];
    // LN(h)
    float s = h, s2 = h * h;
    #pragma unroll
    for (int off = 32; off > 0; off >>= 1) { s += __shfl_xor(s, off); s2 += __shfl_xor(s2, off); }
    if (lane == 0) { redS[wave] = s; redS2[wave] = s2; }
    __syncthreads();
    float mean = (redS[0] + redS[1] + redS[2] + redS[3]) * (1.f / 256.f);
    float m2 = (redS2[0] + redS2[1] + redS2[2] + redS2[3]) * (1.f / 256.f);
    float rstd = rsqrtf(m2 - mean * mean + 1e-5f);
    y0[tid] = (h - mean) * rstd * mlp_ln_g[tid] + mlp_ln_b[tid];
    __syncthreads();
    float a0 = mlp_b1[tid], a1 = mlp_b1[tid + 256], a2 = mlp_b1[tid + 512], a3 = mlp_b1[tid + 768];
    for (int j = 0; j < 256; j++) {
        float yv = y0[j];
        const float* w = mlp_w1 + (size_t)j * 1024;
        a0 += yv * w[tid]; a1 += yv * w[tid + 256]; a2 += yv * w[tid + 512]; a3 += yv * w[tid + 768];
    }
    t1[tid] = fmaxf(a0, 0.f); t1[tid + 256] = fmaxf(a1, 0.f);
    t1[tid + 512] = fmaxf(a2, 0.f); t1[tid + 768] = fmaxf(a3, 0.f);
    __syncthreads();
    float yv = mlp_b2[tid];
    for (int j = 0; j < 1024; j++) yv += t1[j] * mlp_w2[(size_t)j * 256 + tid];
    slots[bs * 256 + tid] = h + yv;
}

// ---------------- attn output (normalized) ----------------
__global__ void attn_out_k(const float* __restrict__ attn_raw, const float* __restrict__ denom,
                           float* __restrict__ out_attn)
{
    int b = blockIdx.y;
    int idx = blockIdx.x * 256 + threadIdx.x; // 0..32767
    int s = idx >> 12;
    out_attn[(size_t)b * Sc * Nc_ + idx] = attn_raw[(size_t)b * Sc * Nc_ + idx] / denom[b * 8 + s];
}

// ---------------- out = slots@fin_w + fin_b ----------------
__global__ void out_k(const float* __restrict__ slots, const float* __restrict__ fin_w,
                      const float* __restrict__ fin_b, float* __restrict__ outp)
{
    int bs = blockIdx.x;
    int tid = threadIdx.x;
    __shared__ float sl[256];
    sl[tid] = slots[bs * 256 + tid];
    __syncthreads();
    float acc = fin_b[tid];
    for (int j = 0; j < 256; j++) acc += sl[j] * fin_w[j * 256 + tid];
    outp[bs * 256 + tid] = acc;
}

extern "C" void kernel_launch(void* const* d_in, const int* in_sizes, int n_in,
                              void* d_out, int out_size, void* d_ws, size_t ws_size,
                              hipStream_t stream)
{
    const float* inputs       = (const float*)d_in[0];
    const float* point_coords = (const float*)d_in[1];
    const float* slots_param  = (const float*)d_in[2];
    const float* Sp0          = (const float*)d_in[3];
    const float* Ss0          = (const float*)d_in[4];
    const float* Qw           = (const float*)d_in[5];
    const float* Kw           = (const float*)d_in[6];
    const float* Vw           = (const float*)d_in[7];
    const float* norm_g       = (const float*)d_in[8];
    const float* norm_b       = (const float*)d_in[9];
    const float* gw           = (const float*)d_in[10];
    const float* gb           = (const float*)d_in[11];
    const float* fw1          = (const float*)d_in[12];
    const float* fb1          = (const float*)d_in[13];
    const float* fw2          = (const float*)d_in[14];
    const float* fb2          = (const float*)d_in[15];
    const float* gru_wi       = (const float*)d_in[16];
    const float* gru_wh       = (const float*)d_in[17];
    const float* gru_bi       = (const float*)d_in[18];
    const float* gru_bh       = (const float*)d_in[19];
    const float* mlp_ln_g     = (const float*)d_in[20];
    const float* mlp_ln_b     = (const float*)d_in[21];
    const float* mlp_w1       = (const float*)d_in[22];
    const float* mlp_b1       = (const float*)d_in[23];
    const float* mlp_w2       = (const float*)d_in[24];
    const float* mlp_b2       = (const float*)d_in[25];
    const float* im_ln1_g     = (const float*)d_in[26];
    const float* im_ln1_b     = (const float*)d_in[27];
    const float* im_w1        = (const float*)d_in[28];
    const float* im_b1        = (const float*)d_in[29];
    const float* im_w2        = (const float*)d_in[30];
    const float* im_b2        = (const float*)d_in[31];
    const float* im_ln2_g     = (const float*)d_in[32];
    const float* im_ln2_b     = (const float*)d_in[33];
    const float* fin_w        = (const float*)d_in[34];
    const float* fin_b        = (const float*)d_in[35];

    float* W = (float*)d_ws;
    float* h1c   = W;                         // 4096*768   = 3,145,728 (chunk buffer)
    float* x2    = W + 3145728;               // 16384*256  = 4,194,304
    float* AKV   = W + 7340032;               // 16384*512  = 8,388,608
    float* st1   = W + 15728640;              // 32768
    float* st2   = W + 15761408;              // 32768
    float* KVF   = W + 15794176;              // 131072
    float* G3    = W + 15925248;              // 768
    float* bias2 = W + 15926016;              // 512
    float* slots = W + 15926528;              // 8192
    float* Spb   = W + 15934720;              // 96
    float* Ssb   = W + 15934816;              // 96
    float* w2q   = W + 15934912;              // 8192
    float* qcb   = W + 15943104;              // 32
    float* invv  = W + 15943136;              // 96
    float* dots  = W + 15943232;              // 131072
    float* attn_raw = W + 16074304;           // 131072
    float* denom = W + 16205376;              // 32   -- start of zeroed region
    float* u1acc = W + 16205408;              // 8192
    float* Spacc = W + 16213600;              // 96
    float* Epacc = W + 16213696;              // 96   -- end 16,213,792 floats (~65 MB)

    // ---- precompute folded weights ----
    kvf_k<<<256, 512, 0, stream>>>(Kw, Vw, fw1, KVF);
    g3b_k<<<1, 256, 0, stream>>>(gw, gb, fb1, fw1, G3, bias2);
    init_k<<<32, 256, 0, stream>>>(slots_param, Sp0, Ss0, slots, Spb, Ssb);

    // ---- input MLP ----
    ln_stats_k<<<4096, 256, 0, stream>>>(inputs, st1, DINc);
    for (int c = 0; c < 4; c++) {
        const float* Ain = inputs + (size_t)c * 4096 * DINc;
        const float* stc = st1 + (size_t)c * 4096 * 2;
        gemm_k<true, true><<<dim3(DINc / 64, 4096 / 64), 256, 0, stream>>>(
            Ain, im_w1, im_b1, h1c, 4096, DINc, DINc, stc, im_ln1_g, im_ln1_b);
        gemm_k<false, false><<<dim3(Dc / 64, 4096 / 64), 256, 0, stream>>>(
            h1c, im_w2, im_b2, x2 + (size_t)c * 4096 * Dc, 4096, Dc, DINc,
            nullptr, nullptr, nullptr);
    }
    ln_stats_k<<<4096, 256, 0, stream>>>(x2, st2, Dc);
    gemm_k<true, false><<<dim3(512 / 64, 16384 / 64), 256, 0, stream>>>(
        x2, KVF, bias2, AKV, 16384, 512, Dc, st2, im_ln2_g, im_ln2_b);

    float* out_slots = (float*)d_out;
    float* out_attn  = (float*)d_out + Bc * Sc * Dc;

    // ---- iteration loop ----
    for (int t = 0; t <= 3; t++) {
        hipMemsetAsync(denom, 0, (32 + 8192 + 96 + 96) * sizeof(float), stream);
        qprep_k<<<32, 256, 0, stream>>>(slots, norm_g, norm_b, Qw, fw2, fb2, Ssb, w2q, qcb, invv);
        phaseA_k<<<dim3(64, 4), 256, 0, stream>>>(AKV, point_coords, G3, w2q, qcb, Spb, invv, dots);
        softmax_k<<<dim3(16, 4), 256, 0, stream>>>(dots, attn_raw, denom);
        if (t < 3) {
            phaseB_k<<<dim3(64, 4), 256, 0, stream>>>(AKV, point_coords, G3, attn_raw, denom,
                                                      Spb, invv, u1acc, Spacc, Epacc);
            gru_k<<<32, 256, 0, stream>>>(u1acc, fw2, fb2, Spacc, Epacc, gru_wi, gru_wh,
                                          gru_bi, gru_bh, mlp_ln_g, mlp_ln_b, mlp_w1, mlp_b1,
                                          mlp_w2, mlp_b2, slots, Spb, Ssb);
        } else {
            attn_out_k<<<dim3(128, 4), 256, 0, stream>>>(attn_raw, denom, out_attn);
            out_k<<<32, 256, 0, stream>>>(slots, fin_w, fin_b, out_slots);
        }
    }
}

// Round 2
// 826.002 us; speedup vs baseline: 1.5943x; 1.5943x over previous
//
#include <hip/hip_runtime.h>
#include <math.h>

typedef unsigned short u16;
typedef short short8 __attribute__((ext_vector_type(8)));
typedef float f32x4 __attribute__((ext_vector_type(4)));

#define Bc 4
#define Nc_ 4096
#define DINc 768
#define Dc 256
#define Sc 8
#define SCALEc 0.0625f
#define EPSc 1e-8f

__device__ __forceinline__ u16 f2bf(float f) {
    union { float f; unsigned u; } x; x.f = f;
    unsigned r = x.u + 0x7fffu + ((x.u >> 16) & 1u);
    return (u16)(r >> 16);
}

#define GLDS(g, l) __builtin_amdgcn_global_load_lds( \
    (const __attribute__((address_space(1))) void*)(g), \
    (__attribute__((address_space(3))) void*)(l), 16, 0, 0)

// ================= bf16 MFMA GEMM: C[M][N] = A[M][K] @ Bt[N][K]^T + bias ================
template<bool RELU, bool BF16OUT>
__global__ __launch_bounds__(256) void mfma_gemm(
    const u16* __restrict__ A, const u16* __restrict__ Bt,
    const float* __restrict__ bias, void* __restrict__ Cv,
    int M, int N, int K)
{
    __shared__ u16 lA[128 * 32];
    __shared__ u16 lB[128 * 32];
    const int tid = threadIdx.x;
    const int lane = tid & 63, w = tid >> 6;
    const int wm = w >> 1, wn = w & 1;
    const int m0 = blockIdx.y * 128, n0 = blockIdx.x * 128;

    f32x4 acc[4][4];
    #pragma unroll
    for (int mi = 0; mi < 4; mi++)
        #pragma unroll
        for (int ni = 0; ni < 4; ni++)
            #pragma unroll
            for (int r = 0; r < 4; r++) acc[mi][ni][r] = 0.f;

    const int arow = (w << 5) + (lane >> 2);      // wave-local staging row
    const int achk = (lane & 3) << 3;             // 8-elem (16B) chunk in k
    const size_t K16 = (size_t)K << 4;            // 16 rows worth of elems
    const u16* ga = A + (size_t)(m0 + arow) * K + achk;
    const u16* gb = Bt + (size_t)(n0 + arow) * K + achk;
    u16* la0 = &lA[w << 10];
    u16* la1 = &lA[(w << 10) + 512];
    u16* lb0 = &lB[w << 10];
    u16* lb1 = &lB[(w << 10) + 512];

    for (int k0 = 0; k0 < K; k0 += 32) {
        GLDS(ga + k0, la0);
        GLDS(ga + k0 + K16, la1);
        GLDS(gb + k0, lb0);
        GLDS(gb + k0 + K16, lb1);
        asm volatile("s_waitcnt vmcnt(0)" ::: "memory");
        __syncthreads();
        short8 af[4], bf[4];
        #pragma unroll
        for (int mi = 0; mi < 4; mi++)
            af[mi] = *(const short8*)&lA[((wm << 6) + (mi << 4) + (lane & 15)) * 32 + ((lane >> 4) << 3)];
        #pragma unroll
        for (int ni = 0; ni < 4; ni++)
            bf[ni] = *(const short8*)&lB[((wn << 6) + (ni << 4) + (lane & 15)) * 32 + ((lane >> 4) << 3)];
        #pragma unroll
        for (int mi = 0; mi < 4; mi++)
            #pragma unroll
            for (int ni = 0; ni < 4; ni++)
                acc[mi][ni] = __builtin_amdgcn_mfma_f32_16x16x32_bf16(af[mi], bf[ni], acc[mi][ni], 0, 0, 0);
        __syncthreads();
    }

    const int ccol = lane & 15;
    const int crow = (lane >> 4) << 2;
    #pragma unroll
    for (int mi = 0; mi < 4; mi++) {
        #pragma unroll
        for (int ni = 0; ni < 4; ni++) {
            int colg = n0 + (wn << 6) + (ni << 4) + ccol;
            float bv = bias ? bias[colg] : 0.f;
            #pragma unroll
            for (int r = 0; r < 4; r++) {
                int rowg = m0 + (wm << 6) + (mi << 4) + crow + r;
                float v = acc[mi][ni][r] + bv;
                if (RELU) v = fmaxf(v, 0.f);
                if (BF16OUT) ((u16*)Cv)[(size_t)rowg * N + colg] = f2bf(v);
                else         ((float*)Cv)[(size_t)rowg * N + colg] = v;
            }
        }
    }
}

// ============== fused row-LayerNorm + bf16 convert (one block per row, K<=768) ==========
__global__ __launch_bounds__(256) void lncvt_k(
    const float* __restrict__ X, const float* __restrict__ g, const float* __restrict__ b,
    u16* __restrict__ out, int K)
{
    int row = blockIdx.x, tid = threadIdx.x, lane = tid & 63, wave = tid >> 6;
    __shared__ float buf[768];
    __shared__ float rs[4], rs2[4];
    float s = 0.f, s2 = 0.f;
    for (int k = tid; k < K; k += 256) {
        float v = X[(size_t)row * K + k];
        buf[k] = v; s += v; s2 += v * v;
    }
    #pragma unroll
    for (int off = 32; off > 0; off >>= 1) { s += __shfl_xor(s, off); s2 += __shfl_xor(s2, off); }
    if (lane == 0) { rs[wave] = s; rs2[wave] = s2; }
    __syncthreads();
    float inv = 1.f / (float)K;
    float mean = (rs[0] + rs[1] + rs[2] + rs[3]) * inv;
    float m2 = (rs2[0] + rs2[1] + rs2[2] + rs2[3]) * inv;
    float rstd = rsqrtf(m2 - mean * mean + 1e-5f);
    for (int k = tid; k < K; k += 256)
        out[(size_t)row * K + k] = f2bf((buf[k] - mean) * rstd * g[k] + b[k]);
}

// ============== plain f32 -> bf16 convert ==============
__global__ void cvt_k(const float* __restrict__ in, u16* __restrict__ out)
{
    int i = blockIdx.x * 256 + threadIdx.x;
    out[i] = f2bf(in[i]);
}

// ============== transpose + convert: in[R][C] f32 -> out[C][R] bf16 ==============
__global__ __launch_bounds__(256) void tcvt_k(const float* __restrict__ in, u16* __restrict__ out,
                                              int R, int C)
{
    __shared__ float tile[32][33];
    int r0 = blockIdx.y * 32, c0 = blockIdx.x * 32;
    int tx = threadIdx.x & 31, ty = threadIdx.x >> 5;
    #pragma unroll
    for (int i = 0; i < 32; i += 8)
        tile[ty + i][tx] = in[(size_t)(r0 + ty + i) * C + c0 + tx];
    __syncthreads();
    #pragma unroll
    for (int i = 0; i < 32; i += 8)
        out[(size_t)(c0 + ty + i) * R + r0 + tx] = f2bf(tile[tx][ty + i]);
}

// ---------------- KVF = [Kw@fw1 | Vw@fw1]  (256 x 512, fp32) ----------------
__global__ void kvf_k(const float* __restrict__ Kw, const float* __restrict__ Vw,
                      const float* __restrict__ fw1, float* __restrict__ KVF)
{
    int k = blockIdx.x;
    int j = threadIdx.x;
    const float* Mrow = (j < 256 ? Kw : Vw) + k * 256;
    int jj = j & 255;
    float acc = 0.f;
    for (int d = 0; d < 256; d++) acc += Mrow[d] * fw1[d * 256 + jj];
    KVF[k * 512 + j] = acc;
}

// ---------------- G3 = gw@fw1 (3x256), bias2 = dup(gb@fw1+fb1) (512) ----------
__global__ void g3b_k(const float* __restrict__ gw, const float* __restrict__ gb,
                      const float* __restrict__ fb1, const float* __restrict__ fw1,
                      float* __restrict__ G3, float* __restrict__ bias2)
{
    int j = threadIdx.x;
    float g0 = 0, g1 = 0, g2 = 0, bb = 0;
    for (int d = 0; d < 256; d++) {
        float f = fw1[d * 256 + j];
        g0 += gw[d] * f;
        g1 += gw[256 + d] * f;
        g2 += gw[512 + d] * f;
        bb += gb[d] * f;
    }
    G3[j] = g0; G3[256 + j] = g1; G3[512 + j] = g2;
    float b1v = fb1[j] + bb;
    bias2[j] = b1v; bias2[256 + j] = b1v;
}

// ---------------- qv = Qw @ fb2 (256) ----------------
__global__ void qv_k(const float* __restrict__ Qw, const float* __restrict__ fb2,
                     float* __restrict__ qv)
{
    __shared__ float f[256];
    int tid = threadIdx.x;
    f[tid] = fb2[tid];
    __syncthreads();
    float a = 0.f;
    for (int d = 0; d < 256; d++) a += Qw[tid * 256 + d] * f[d];
    qv[tid] = a;
}

// ---------------- init slots / S_p / S_s state ----------------
__global__ void init_k(const float* __restrict__ slots_param, const float* __restrict__ Sp0,
                       const float* __restrict__ Ss0, float* __restrict__ slots,
                       float* __restrict__ Spb, float* __restrict__ Ssb)
{
    int idx = blockIdx.x * 256 + threadIdx.x;
    slots[idx] = slots_param[idx & 2047];
    if (idx < Bc * Sc * 3) {
        int s3 = idx % 24;
        Spb[idx] = Sp0[s3];
        Ssb[idx] = Ss0[s3];
    }
}

// ---------------- qprep: w2q = LN(slots)@QF ; qc = LN(slots).qv ; invv ----------
__global__ __launch_bounds__(256) void qprep2_k(
    const float* __restrict__ slots, const float* __restrict__ norm_g, const float* __restrict__ norm_b,
    const float* __restrict__ QF, const float* __restrict__ qv, const float* __restrict__ Ssb,
    float* __restrict__ w2q, float* __restrict__ qc, float* __restrict__ invv)
{
    int bs = blockIdx.x, tid = threadIdx.x, lane = tid & 63, wave = tid >> 6;
    __shared__ float sl[256];
    __shared__ float redS[4], redS2[4];
    float v = slots[bs * 256 + tid];
    float s = v, s2 = v * v;
    #pragma unroll
    for (int off = 32; off > 0; off >>= 1) { s += __shfl_xor(s, off); s2 += __shfl_xor(s2, off); }
    if (lane == 0) { redS[wave] = s; redS2[wave] = s2; }
    __syncthreads();
    float mean = (redS[0] + redS[1] + redS[2] + redS[3]) * (1.f / 256.f);
    float m2 = (redS2[0] + redS2[1] + redS2[2] + redS2[3]) * (1.f / 256.f);
    float rstd = rsqrtf(m2 - mean * mean + 1e-5f);
    float slv = (v - mean) * rstd * norm_g[tid] + norm_b[tid];
    sl[tid] = slv;
    __syncthreads();
    float wq = 0.f;
    for (int i = 0; i < 256; i++) wq += sl[i] * QF[i * 256 + tid];
    w2q[bs * 256 + tid] = wq;
    float c = slv * qv[tid];
    #pragma unroll
    for (int off = 32; off > 0; off >>= 1) c += __shfl_xor(c, off);
    __syncthreads();
    if (lane == 0) redS[wave] = c;
    __syncthreads();
    if (tid == 0) qc[bs] = redS[0] + redS[1] + redS[2] + redS[3];
    if (tid < 3) invv[bs * 3 + tid] = 1.f / (Ssb[bs * 3 + tid] * 5.0f + EPSc);
}

// ---------------- phase A: dots ----------------
__global__ __launch_bounds__(256) void phaseA_k(
    const float* __restrict__ AKV, const float* __restrict__ P,
    const float* __restrict__ G3, const float* __restrict__ w2q,
    const float* __restrict__ qc, const float* __restrict__ Spb, const float* __restrict__ invv,
    float* __restrict__ dots)
{
    int b = blockIdx.y;
    int tid = threadIdx.x, wave = tid >> 6, lane = tid & 63;
    const float4* G3f = (const float4*)G3;
    float4 g0 = G3f[lane], g1 = G3f[64 + lane], g2 = G3f[128 + lane];
    float4 wqr[8];
    float sp[8][3], iv[8][3], qcr[8];
    #pragma unroll
    for (int s = 0; s < 8; s++) {
        wqr[s] = ((const float4*)w2q)[(b * 8 + s) * 64 + lane];
        sp[s][0] = Spb[(b * 8 + s) * 3 + 0];
        sp[s][1] = Spb[(b * 8 + s) * 3 + 1];
        sp[s][2] = Spb[(b * 8 + s) * 3 + 2];
        iv[s][0] = invv[(b * 8 + s) * 3 + 0];
        iv[s][1] = invv[(b * 8 + s) * 3 + 1];
        iv[s][2] = invv[(b * 8 + s) * 3 + 2];
        qcr[s] = qc[b * 8 + s];
    }
    for (int i = 0; i < 16; i++) {
        int n = blockIdx.x * 64 + wave * 16 + i;
        size_t base = (size_t)(b * Nc_ + n);
        float4 ak = ((const float4*)(AKV + base * 512))[lane];
        const float* pp = P + base * 3;
        float p0 = pp[0], p1 = pp[1], p2 = pp[2];
        #pragma unroll
        for (int s = 0; s < 8; s++) {
            float r0 = (p0 - sp[s][0]) * iv[s][0];
            float r1 = (p1 - sp[s][1]) * iv[s][1];
            float r2 = (p2 - sp[s][2]) * iv[s][2];
            float h, acc;
            h = fmaxf(ak.x + r0 * g0.x + r1 * g1.x + r2 * g2.x, 0.f); acc  = h * wqr[s].x;
            h = fmaxf(ak.y + r0 * g0.y + r1 * g1.y + r2 * g2.y, 0.f); acc += h * wqr[s].y;
            h = fmaxf(ak.z + r0 * g0.z + r1 * g1.z + r2 * g2.z, 0.f); acc += h * wqr[s].z;
            h = fmaxf(ak.w + r0 * g0.w + r1 * g1.w + r2 * g2.w, 0.f); acc += h * wqr[s].w;
            #pragma unroll
            for (int off = 32; off > 0; off >>= 1) acc += __shfl_xor(acc, off);
            if (lane == 0) dots[(size_t)(b * 8 + s) * Nc_ + n] = (acc + qcr[s]) * SCALEc;
        }
    }
}

// ---------------- softmax over slots + EPS; per-(b,s) denom partials ---------------
__global__ __launch_bounds__(256) void softmax_k(
    const float* __restrict__ dots, float* __restrict__ attn_raw, float* __restrict__ denom)
{
    int b = blockIdx.y;
    int n = blockIdx.x * 256 + threadIdx.x;
    float d_[8];
    #pragma unroll
    for (int s = 0; s < 8; s++) d_[s] = dots[(size_t)(b * 8 + s) * Nc_ + n];
    float mx = d_[0];
    #pragma unroll
    for (int s = 1; s < 8; s++) mx = fmaxf(mx, d_[s]);
    float sum = 0.f;
    #pragma unroll
    for (int s = 0; s < 8; s++) { d_[s] = expf(d_[s] - mx); sum += d_[s]; }
    float inv = 1.f / sum;
    float part[8];
    #pragma unroll
    for (int s = 0; s < 8; s++) {
        float a = d_[s] * inv + EPSc;
        attn_raw[(size_t)(b * 8 + s) * Nc_ + n] = a;
        part[s] = a;
    }
    int lane = threadIdx.x & 63, wave = threadIdx.x >> 6;
    __shared__ float red[4][8];
    #pragma unroll
    for (int s = 0; s < 8; s++) {
        float v = part[s];
        #pragma unroll
        for (int off = 32; off > 0; off >>= 1) v += __shfl_xor(v, off);
        if (lane == 0) red[wave][s] = v;
    }
    __syncthreads();
    if (threadIdx.x < 8) {
        int s = threadIdx.x;
        atomicAdd(&denom[b * 8 + s], red[0][s] + red[1][s] + red[2][s] + red[3][s]);
    }
}

// ---------------- phase B: u1 += attn*relu(AV+rel@G3); Sp/Ep moments -------------------
__global__ __launch_bounds__(256) void phaseB_k(
    const float* __restrict__ AKV, const float* __restrict__ P,
    const float* __restrict__ G3, const float* __restrict__ attn_raw,
    const float* __restrict__ denom, const float* __restrict__ Spb, const float* __restrict__ invv,
    float* __restrict__ u1acc, float* __restrict__ Spacc, float* __restrict__ Epacc)
{
    int b = blockIdx.y;
    int tid = threadIdx.x, wave = tid >> 6, lane = tid & 63;
    __shared__ float uls[4][2048];
    __shared__ float spls[4][8][6];
    const float4* G3f = (const float4*)G3;
    float4 g0 = G3f[lane], g1 = G3f[64 + lane], g2 = G3f[128 + lane];
    float sp[8][3], iv[8][3], idn[8];
    #pragma unroll
    for (int s = 0; s < 8; s++) {
        sp[s][0] = Spb[(b * 8 + s) * 3 + 0];
        sp[s][1] = Spb[(b * 8 + s) * 3 + 1];
        sp[s][2] = Spb[(b * 8 + s) * 3 + 2];
        iv[s][0] = invv[(b * 8 + s) * 3 + 0];
        iv[s][1] = invv[(b * 8 + s) * 3 + 1];
        iv[s][2] = invv[(b * 8 + s) * 3 + 2];
        idn[s] = 1.f / denom[b * 8 + s];
    }
    float au[8][4] = {};
    float asp[3] = {0, 0, 0}, aep[3] = {0, 0, 0};
    for (int i = 0; i < 16; i++) {
        int n = blockIdx.x * 64 + wave * 16 + i;
        size_t base = (size_t)(b * Nc_ + n);
        float4 av = ((const float4*)(AKV + base * 512 + 256))[lane];
        const float* pp = P + base * 3;
        float p0 = pp[0], p1 = pp[1], p2 = pp[2];
        #pragma unroll
        for (int s = 0; s < 8; s++) {
            float a = attn_raw[(size_t)(b * 8 + s) * Nc_ + n] * idn[s];
            float r0 = (p0 - sp[s][0]) * iv[s][0];
            float r1 = (p1 - sp[s][1]) * iv[s][1];
            float r2 = (p2 - sp[s][2]) * iv[s][2];
            float h;
            h = fmaxf(av.x + r0 * g0.x + r1 * g1.x + r2 * g2.x, 0.f); au[s][0] += a * h;
            h = fmaxf(av.y + r0 * g0.y + r1 * g1.y + r2 * g2.y, 0.f); au[s][1] += a * h;
            h = fmaxf(av.z + r0 * g0.z + r1 * g1.z + r2 * g2.z, 0.f); au[s][2] += a * h;
            h = fmaxf(av.w + r0 * g0.w + r1 * g1.w + r2 * g2.w, 0.f); au[s][3] += a * h;
            if (lane == s) {
                asp[0] += a * p0; asp[1] += a * p1; asp[2] += a * p2;
                aep[0] += a * p0 * p0; aep[1] += a * p1 * p1; aep[2] += a * p2 * p2;
            }
        }
    }
    #pragma unroll
    for (int s = 0; s < 8; s++)
        #pragma unroll
        for (int j = 0; j < 4; j++)
            uls[wave][s * 256 + 4 * lane + j] = au[s][j];
    if (lane < 8) {
        #pragma unroll
        for (int i = 0; i < 3; i++) {
            spls[wave][lane][i] = asp[i];
            spls[wave][lane][3 + i] = aep[i];
        }
    }
    __syncthreads();
    for (int idx = tid; idx < 2048; idx += 256) {
        float v = uls[0][idx] + uls[1][idx] + uls[2][idx] + uls[3][idx];
        atomicAdd(&u1acc[b * 2048 + idx], v);
    }
    if (tid < 48) {
        int s = tid / 6, i = tid % 6;
        float v = spls[0][s][i] + spls[1][s][i] + spls[2][s][i] + spls[3][s][i];
        if (i < 3) atomicAdd(&Spacc[b * 24 + s * 3 + i], v);
        else       atomicAdd(&Epacc[b * 24 + s * 3 + (i - 3)], v);
    }
}

// ---------------- slot-update chain: upd = u1@fw2+fb2 (+ Sp/Ss finalize) ---------------
__global__ __launch_bounds__(256) void k_upd(
    const float* __restrict__ u1acc, const float* __restrict__ fw2, const float* __restrict__ fb2,
    const float* __restrict__ Spacc, const float* __restrict__ Epacc,
    float* __restrict__ upd, float* __restrict__ Spb, float* __restrict__ Ssb)
{
    int bs = blockIdx.x, chunk = blockIdx.y;
    int tid = threadIdx.x, c = tid & 31, ks = tid >> 5;
    __shared__ float u1[256];
    __shared__ float part[8][33];
    u1[tid] = u1acc[bs * 256 + tid];
    if (chunk == 0 && tid < 3) {
        float spv = Spacc[bs * 3 + tid];
        float ep = Epacc[bs * 3 + tid];
        Spb[bs * 3 + tid] = spv;
        Ssb[bs * 3 + tid] = sqrtf(fmaxf(ep - spv * spv, 0.f) + EPSc);
    }
    __syncthreads();
    int col = (chunk << 5) + c;
    float p = 0.f;
    int j0 = ks << 5;
    for (int j = j0; j < j0 + 32; j++) p += u1[j] * fw2[(size_t)j * 256 + col];
    part[ks][c] = p;
    __syncthreads();
    if (tid < 32) {
        int col2 = (chunk << 5) + tid;
        float a = fb2[col2];
        #pragma unroll
        for (int r = 0; r < 8; r++) a += part[r][tid];
        upd[bs * 256 + col2] = a;
    }
}

// ---------------- GRU gates -> h ----------------
__global__ __launch_bounds__(256) void k_gates(
    const float* __restrict__ upd, const float* __restrict__ slots,
    const float* __restrict__ gwi, const float* __restrict__ gwh,
    const float* __restrict__ gbi, const float* __restrict__ gbh,
    float* __restrict__ hbuf)
{
    int bs = blockIdx.x, chunk = blockIdx.y;
    int tid = threadIdx.x, c = tid & 31, ks = tid >> 5;
    __shared__ float u[256], sp[256];
    __shared__ float part[6][8][33];
    u[tid] = upd[bs * 256 + tid];
    sp[tid] = slots[bs * 256 + tid];
    __syncthreads();
    int col = (chunk << 5) + c;
    float a0 = 0, a1 = 0, a2 = 0, h0 = 0, h1 = 0, h2 = 0;
    int j0 = ks << 5;
    for (int j = j0; j < j0 + 32; j++) {
        const float* wi = gwi + (size_t)j * 768;
        const float* wh = gwh + (size_t)j * 768;
        float uj = u[j], sj = sp[j];
        a0 += uj * wi[col]; a1 += uj * wi[col + 256]; a2 += uj * wi[col + 512];
        h0 += sj * wh[col]; h1 += sj * wh[col + 256]; h2 += sj * wh[col + 512];
    }
    part[0][ks][c] = a0; part[1][ks][c] = a1; part[2][ks][c] = a2;
    part[3][ks][c] = h0; part[4][ks][c] = h1; part[5][ks][c] = h2;
    __syncthreads();
    if (tid < 32) {
        int col2 = (chunk << 5) + tid;
        float gx0 = gbi[col2], gx1 = gbi[col2 + 256], gx2 = gbi[col2 + 512];
        float gh0 = gbh[col2], gh1 = gbh[col2 + 256], gh2 = gbh[col2 + 512];
        #pragma unroll
        for (int r = 0; r < 8; r++) {
            gx0 += part[0][r][tid]; gx1 += part[1][r][tid]; gx2 += part[2][r][tid];
            gh0 += part[3][r][tid]; gh1 += part[4][r][tid]; gh2 += part[5][r][tid];
        }
        float rg = 1.f / (1.f + expf(-(gx0 + gh0)));
        float zg = 1.f / (1.f + expf(-(gx1 + gh1)));
        float ng = tanhf(gx2 + rg * gh2);
        hbuf[bs * 256 + col2] = (1.f - zg) * ng + zg * sp[col2];
    }
}

// ---------------- mlp1: t1 = relu(LN(h)@w1 + b1)  (LN stats computed in-block) --------
__global__ __launch_bounds__(256) void k_mlp1(
    const float* __restrict__ hbuf, const float* __restrict__ lng, const float* __restrict__ lnb,
    const float* __restrict__ w1, const float* __restrict__ b1, float* __restrict__ t1)
{
    int bs = blockIdx.x, chunk = blockIdx.y;
    int tid = threadIdx.x, lane = tid & 63, wave = tid >> 6;
    int c = tid & 31, ks = tid >> 5;
    __shared__ float y0[256];
    __shared__ float part[8][33];
    __shared__ float rs[4], rs2[4];
    float h = hbuf[bs * 256 + tid];
    float s = h, s2 = h * h;
    #pragma unroll
    for (int off = 32; off > 0; off >>= 1) { s += __shfl_xor(s, off); s2 += __shfl_xor(s2, off); }
    if (lane == 0) { rs[wave] = s; rs2[wave] = s2; }
    __syncthreads();
    float mean = (rs[0] + rs[1] + rs[2] + rs[3]) * (1.f / 256.f);
    float m2 = (rs2[0] + rs2[1] + rs2[2] + rs2[3]) * (1.f / 256.f);
    float rstd = rsqrtf(m2 - mean * mean + 1e-5f);
    y0[tid] = (h - mean) * rstd * lng[tid] + lnb[tid];
    __syncthreads();
    int col = (chunk << 5) + c;
    float p = 0.f;
    int j0 = ks << 5;
    for (int j = j0; j < j0 + 32; j++) p += y0[j] * w1[(size_t)j * 1024 + col];
    part[ks][c] = p;
    __syncthreads();
    if (tid < 32) {
        int col2 = (chunk << 5) + tid;
        float a = b1[col2];
        #pragma unroll
        for (int r = 0; r < 8; r++) a += part[r][tid];
        t1[bs * 1024 + col2] = fmaxf(a, 0.f);
    }
}

// ---------------- mlp2: slots = h + t1@w2 + b2 ----------------
__global__ __launch_bounds__(256) void k_mlp2(
    const float* __restrict__ t1, const float* __restrict__ hbuf,
    const float* __restrict__ w2, const float* __restrict__ b2, float* __restrict__ slots)
{
    int bs = blockIdx.x, chunk = blockIdx.y;
    int tid = threadIdx.x, c = tid & 31, ks = tid >> 5;
    __shared__ float t1s[1024];
    __shared__ float part[8][33];
    for (int i = tid; i < 1024; i += 256) t1s[i] = t1[bs * 1024 + i];
    __syncthreads();
    int col = (chunk << 5) + c;
    float p = 0.f;
    int j0 = ks << 7;
    for (int j = j0; j < j0 + 128; j++) p += t1s[j] * w2[(size_t)j * 256 + col];
    part[ks][c] = p;
    __syncthreads();
    if (tid < 32) {
        int col2 = (chunk << 5) + tid;
        float a = b2[col2] + hbuf[bs * 256 + col2];
        #pragma unroll
        for (int r = 0; r < 8; r++) a += part[r][tid];
        slots[bs * 256 + col2] = a;
    }
}

// ---------------- attn output (normalized) ----------------
__global__ void attn_out_k(const float* __restrict__ attn_raw, const float* __restrict__ denom,
                           float* __restrict__ out_attn)
{
    int b = blockIdx.y;
    int idx = blockIdx.x * 256 + threadIdx.x;
    int s = idx >> 12;
    out_attn[(size_t)b * Sc * Nc_ + idx] = attn_raw[(size_t)b * Sc * Nc_ + idx] / denom[b * 8 + s];
}

// ---------------- out = slots@fin_w + fin_b ----------------
__global__ void out_k(const float* __restrict__ slots, const float* __restrict__ fin_w,
                      const float* __restrict__ fin_b, float* __restrict__ outp)
{
    int bs = blockIdx.x;
    int tid = threadIdx.x;
    __shared__ float sl[256];
    sl[tid] = slots[bs * 256 + tid];
    __syncthreads();
    float acc = fin_b[tid];
    for (int j = 0; j < 256; j++) acc += sl[j] * fin_w[j * 256 + tid];
    outp[bs * 256 + tid] = acc;
}

extern "C" void kernel_launch(void* const* d_in, const int* in_sizes, int n_in,
                              void* d_out, int out_size, void* d_ws, size_t ws_size,
                              hipStream_t stream)
{
    const float* inputs       = (const float*)d_in[0];
    const float* point_coords = (const float*)d_in[1];
    const float* slots_param  = (const float*)d_in[2];
    const float* Sp0          = (const float*)d_in[3];
    const float* Ss0          = (const float*)d_in[4];
    const float* Qw           = (const float*)d_in[5];
    const float* Kw           = (const float*)d_in[6];
    const float* Vw           = (const float*)d_in[7];
    const float* norm_g       = (const float*)d_in[8];
    const float* norm_b       = (const float*)d_in[9];
    const float* gw           = (const float*)d_in[10];
    const float* gb           = (const float*)d_in[11];
    const float* fw1          = (const float*)d_in[12];
    const float* fb1          = (const float*)d_in[13];
    const float* fw2          = (const float*)d_in[14];
    const float* fb2          = (const float*)d_in[15];
    const float* gru_wi       = (const float*)d_in[16];
    const float* gru_wh       = (const float*)d_in[17];
    const float* gru_bi       = (const float*)d_in[18];
    const float* gru_bh       = (const float*)d_in[19];
    const float* mlp_ln_g     = (const float*)d_in[20];
    const float* mlp_ln_b     = (const float*)d_in[21];
    const float* mlp_w1       = (const float*)d_in[22];
    const float* mlp_b1       = (const float*)d_in[23];
    const float* mlp_w2       = (const float*)d_in[24];
    const float* mlp_b2       = (const float*)d_in[25];
    const float* im_ln1_g     = (const float*)d_in[26];
    const float* im_ln1_b     = (const float*)d_in[27];
    const float* im_w1        = (const float*)d_in[28];
    const float* im_b1        = (const float*)d_in[29];
    const float* im_w2        = (const float*)d_in[30];
    const float* im_b2        = (const float*)d_in[31];
    const float* im_ln2_g     = (const float*)d_in[32];
    const float* im_ln2_b     = (const float*)d_in[33];
    const float* fin_w        = (const float*)d_in[34];
    const float* fin_b        = (const float*)d_in[35];

    float* W = (float*)d_ws;
    float* AKV    = W;                        // 8,388,608 f (final)
    u16*   Abf    = (u16*)(W);                // chunk A bf16 (aliases AKV, dead by gemm3)
    u16*   h1bf   = (u16*)(W + 1572864);      // chunk hidden bf16 (aliases AKV)
    float* x2     = W + 8388608;              // 16384x256 f32
    u16*   x2bf   = (u16*)(W + 12582912);     // 16384x256 bf16 (LN applied)
    float* KVF    = W + 14680064;             // 256x512 f32
    u16*   KVFbt  = (u16*)(W + 14811136);     // [512][256] bf16
    u16*   W1bt   = (u16*)(W + 14876672);     // [768][768] bf16
    u16*   W2bt   = (u16*)(W + 15171584);     // [256][768] bf16
    u16*   Qwbf   = (u16*)(W + 15269888);     // [256][256] bf16
    u16*   fw2bf  = (u16*)(W + 15302656);     // [256][256] bf16
    float* QF     = W + 15335424;             // 256x256 f32
    float* qv     = W + 15400960;             // 256
    float* G3     = W + 15401216;             // 768
    float* bias2  = W + 15401984;             // 512
    float* slots  = W + 15402496;             // 8192
    float* Spb    = W + 15410688;             // 96
    float* Ssb    = W + 15410784;             // 96
    float* w2q    = W + 15410880;             // 8192
    float* qcb    = W + 15419072;             // 32
    float* invv   = W + 15419104;             // 96
    float* dots   = W + 15419200;             // 131072
    float* attn_raw = W + 15550272;           // 131072
    float* denom  = W + 15681344;             // 32  -- memset region start
    float* u1acc  = W + 15681376;             // 8192
    float* Spacc  = W + 15689568;             // 96
    float* Epacc  = W + 15689664;             // 96  -- memset region end (8416 f)
    float* updb   = W + 15689760;             // 8192
    float* hbuf   = W + 15697952;             // 8192
    float* t1buf  = W + 15706144;             // 32768

    // ---- one-time precompute ----
    kvf_k<<<256, 512, 0, stream>>>(Kw, Vw, fw1, KVF);
    g3b_k<<<1, 256, 0, stream>>>(gw, gb, fb1, fw1, G3, bias2);
    init_k<<<32, 256, 0, stream>>>(slots_param, Sp0, Ss0, slots, Spb, Ssb);
    qv_k<<<1, 256, 0, stream>>>(Qw, fb2, qv);
    cvt_k<<<256, 256, 0, stream>>>(Qw, Qwbf);
    cvt_k<<<256, 256, 0, stream>>>(fw2, fw2bf);
    tcvt_k<<<dim3(24, 24), 256, 0, stream>>>(im_w1, W1bt, 768, 768);
    tcvt_k<<<dim3(8, 24), 256, 0, stream>>>(im_w2, W2bt, 768, 256);
    tcvt_k<<<dim3(16, 8), 256, 0, stream>>>(KVF, KVFbt, 256, 512);
    mfma_gemm<false, false><<<dim3(2, 2), 256, 0, stream>>>(Qwbf, fw2bf, nullptr, QF, 256, 256, 256);

    // ---- input MLP (bf16 MFMA, chunked over M to fit workspace) ----
    for (int ch = 0; ch < 4; ch++) {
        const float* Xc = inputs + (size_t)ch * 4096 * DINc;
        lncvt_k<<<4096, 256, 0, stream>>>(Xc, im_ln1_g, im_ln1_b, Abf, DINc);
        mfma_gemm<true, true><<<dim3(6, 32), 256, 0, stream>>>(Abf, W1bt, im_b1, h1bf, 4096, 768, 768);
        mfma_gemm<false, false><<<dim3(2, 32), 256, 0, stream>>>(h1bf, W2bt, im_b2,
            x2 + (size_t)ch * 4096 * Dc, 4096, 256, 768);
    }
    lncvt_k<<<16384, 256, 0, stream>>>(x2, im_ln2_g, im_ln2_b, x2bf, 256);
    mfma_gemm<false, false><<<dim3(4, 128), 256, 0, stream>>>(x2bf, KVFbt, bias2, AKV, 16384, 512, 256);

    float* out_slots = (float*)d_out;
    float* out_attn  = (float*)d_out + Bc * Sc * Dc;

    // ---- iteration loop ----
    for (int t = 0; t <= 3; t++) {
        hipMemsetAsync(denom, 0, 8416 * sizeof(float), stream);
        qprep2_k<<<32, 256, 0, stream>>>(slots, norm_g, norm_b, QF, qv, Ssb, w2q, qcb, invv);
        phaseA_k<<<dim3(64, 4), 256, 0, stream>>>(AKV, point_coords, G3, w2q, qcb, Spb, invv, dots);
        softmax_k<<<dim3(16, 4), 256, 0, stream>>>(dots, attn_raw, denom);
        if (t < 3) {
            phaseB_k<<<dim3(64, 4), 256, 0, stream>>>(AKV, point_coords, G3, attn_raw, denom,
                                                      Spb, invv, u1acc, Spacc, Epacc);
            k_upd<<<dim3(32, 8), 256, 0, stream>>>(u1acc, fw2, fb2, Spacc, Epacc, updb, Spb, Ssb);
            k_gates<<<dim3(32, 8), 256, 0, stream>>>(updb, slots, gru_wi, gru_wh, gru_bi, gru_bh, hbuf);
            k_mlp1<<<dim3(32, 32), 256, 0, stream>>>(hbuf, mlp_ln_g, mlp_ln_b, mlp_w1, mlp_b1, t1buf);
            k_mlp2<<<dim3(32, 8), 256, 0, stream>>>(t1buf, hbuf, mlp_w2, mlp_b2, slots);
        } else {
            attn_out_k<<<dim3(128, 4), 256, 0, stream>>>(attn_raw, denom, out_attn);
            out_k<<<32, 256, 0, stream>>>(slots, fin_w, fin_b, out_slots);
        }
    }
}

// Round 3
// 580.923 us; speedup vs baseline: 2.2669x; 1.4219x over previous
//
#include <hip/hip_runtime.h>
#include <math.h>

typedef unsigned short u16;
typedef short short8 __attribute__((ext_vector_type(8)));
typedef float f32x4 __attribute__((ext_vector_type(4)));

#define Bc 4
#define Nc_ 4096
#define DINc 768
#define Dc 256
#define Sc 8
#define SCALEc 0.0625f
#define EPSc 1e-8f

__device__ __forceinline__ u16 f2bf(float f) {
    union { float f; unsigned u; } x; x.f = f;
    unsigned r = x.u + 0x7fffu + ((x.u >> 16) & 1u);
    return (u16)(r >> 16);
}

#define GLDS(g, l) __builtin_amdgcn_global_load_lds( \
    (const __attribute__((address_space(1))) void*)(g), \
    (__attribute__((address_space(3))) void*)(l), 16, 0, 0)

// ================= bf16 MFMA GEMM: C[M][N] = A[M][K] @ Bt[N][K]^T + bias ================
template<bool RELU, bool BF16OUT>
__global__ __launch_bounds__(256) void mfma_gemm(
    const u16* __restrict__ A, const u16* __restrict__ Bt,
    const float* __restrict__ bias, void* __restrict__ Cv,
    int M, int N, int K)
{
    __shared__ u16 lA[128 * 32];
    __shared__ u16 lB[128 * 32];
    const int tid = threadIdx.x;
    const int lane = tid & 63, w = tid >> 6;
    const int wm = w >> 1, wn = w & 1;
    const int m0 = blockIdx.y * 128, n0 = blockIdx.x * 128;

    f32x4 acc[4][4];
    #pragma unroll
    for (int mi = 0; mi < 4; mi++)
        #pragma unroll
        for (int ni = 0; ni < 4; ni++)
            #pragma unroll
            for (int r = 0; r < 4; r++) acc[mi][ni][r] = 0.f;

    const int arow = (w << 5) + (lane >> 2);
    const int achk = (lane & 3) << 3;
    const size_t K16 = (size_t)K << 4;
    const u16* ga = A + (size_t)(m0 + arow) * K + achk;
    const u16* gb = Bt + (size_t)(n0 + arow) * K + achk;
    u16* la0 = &lA[w << 10];
    u16* la1 = &lA[(w << 10) + 512];
    u16* lb0 = &lB[w << 10];
    u16* lb1 = &lB[(w << 10) + 512];

    for (int k0 = 0; k0 < K; k0 += 32) {
        GLDS(ga + k0, la0);
        GLDS(ga + k0 + K16, la1);
        GLDS(gb + k0, lb0);
        GLDS(gb + k0 + K16, lb1);
        asm volatile("s_waitcnt vmcnt(0)" ::: "memory");
        __syncthreads();
        short8 af[4], bf[4];
        #pragma unroll
        for (int mi = 0; mi < 4; mi++)
            af[mi] = *(const short8*)&lA[((wm << 6) + (mi << 4) + (lane & 15)) * 32 + ((lane >> 4) << 3)];
        #pragma unroll
        for (int ni = 0; ni < 4; ni++)
            bf[ni] = *(const short8*)&lB[((wn << 6) + (ni << 4) + (lane & 15)) * 32 + ((lane >> 4) << 3)];
        #pragma unroll
        for (int mi = 0; mi < 4; mi++)
            #pragma unroll
            for (int ni = 0; ni < 4; ni++)
                acc[mi][ni] = __builtin_amdgcn_mfma_f32_16x16x32_bf16(af[mi], bf[ni], acc[mi][ni], 0, 0, 0);
        __syncthreads();
    }

    const int ccol = lane & 15;
    const int crow = (lane >> 4) << 2;
    #pragma unroll
    for (int mi = 0; mi < 4; mi++) {
        #pragma unroll
        for (int ni = 0; ni < 4; ni++) {
            int colg = n0 + (wn << 6) + (ni << 4) + ccol;
            float bv = bias ? bias[colg] : 0.f;
            #pragma unroll
            for (int r = 0; r < 4; r++) {
                int rowg = m0 + (wm << 6) + (mi << 4) + crow + r;
                float v = acc[mi][ni][r] + bv;
                if (RELU) v = fmaxf(v, 0.f);
                if (BF16OUT) ((u16*)Cv)[(size_t)rowg * N + colg] = f2bf(v);
                else         ((float*)Cv)[(size_t)rowg * N + colg] = v;
            }
        }
    }
}

// ============== fused row-LayerNorm + bf16 convert ==============
__global__ __launch_bounds__(256) void lncvt_k(
    const float* __restrict__ X, const float* __restrict__ g, const float* __restrict__ b,
    u16* __restrict__ out, int K)
{
    int row = blockIdx.x, tid = threadIdx.x, lane = tid & 63, wave = tid >> 6;
    __shared__ float buf[768];
    __shared__ float rs[4], rs2[4];
    float s = 0.f, s2 = 0.f;
    for (int k = tid; k < K; k += 256) {
        float v = X[(size_t)row * K + k];
        buf[k] = v; s += v; s2 += v * v;
    }
    #pragma unroll
    for (int off = 32; off > 0; off >>= 1) { s += __shfl_xor(s, off); s2 += __shfl_xor(s2, off); }
    if (lane == 0) { rs[wave] = s; rs2[wave] = s2; }
    __syncthreads();
    float inv = 1.f / (float)K;
    float mean = (rs[0] + rs[1] + rs[2] + rs[3]) * inv;
    float m2 = (rs2[0] + rs2[1] + rs2[2] + rs2[3]) * inv;
    float rstd = rsqrtf(m2 - mean * mean + 1e-5f);
    for (int k = tid; k < K; k += 256)
        out[(size_t)row * K + k] = f2bf((buf[k] - mean) * rstd * g[k] + b[k]);
}

// ============== plain f32 -> bf16 convert ==============
__global__ void cvt_k(const float* __restrict__ in, u16* __restrict__ out)
{
    int i = blockIdx.x * 256 + threadIdx.x;
    out[i] = f2bf(in[i]);
}

// ============== transpose + convert: in[R][C] f32 -> out[C][R] bf16 ==============
__global__ __launch_bounds__(256) void tcvt_k(const float* __restrict__ in, u16* __restrict__ out,
                                              int R, int C)
{
    __shared__ float tile[32][33];
    int r0 = blockIdx.y * 32, c0 = blockIdx.x * 32;
    int tx = threadIdx.x & 31, ty = threadIdx.x >> 5;
    #pragma unroll
    for (int i = 0; i < 32; i += 8)
        tile[ty + i][tx] = in[(size_t)(r0 + ty + i) * C + c0 + tx];
    __syncthreads();
    #pragma unroll
    for (int i = 0; i < 32; i += 8)
        out[(size_t)(c0 + ty + i) * R + r0 + tx] = f2bf(tile[tx][ty + i]);
}

// ---------------- KVF = [Kw@fw1 | Vw@fw1]  (256 x 512, fp32) ----------------
__global__ void kvf_k(const float* __restrict__ Kw, const float* __restrict__ Vw,
                      const float* __restrict__ fw1, float* __restrict__ KVF)
{
    int k = blockIdx.x;
    int j = threadIdx.x;
    const float* Mrow = (j < 256 ? Kw : Vw) + k * 256;
    int jj = j & 255;
    float acc = 0.f;
    for (int d = 0; d < 256; d++) acc += Mrow[d] * fw1[d * 256 + jj];
    KVF[k * 512 + j] = acc;
}

// ---------------- G3 = gw@fw1 (3x256), bias2 = dup(gb@fw1+fb1) (512) ----------
__global__ void g3b_k(const float* __restrict__ gw, const float* __restrict__ gb,
                      const float* __restrict__ fb1, const float* __restrict__ fw1,
                      float* __restrict__ G3, float* __restrict__ bias2)
{
    int j = threadIdx.x;
    float g0 = 0, g1 = 0, g2 = 0, bb = 0;
    for (int d = 0; d < 256; d++) {
        float f = fw1[d * 256 + j];
        g0 += gw[d] * f;
        g1 += gw[256 + d] * f;
        g2 += gw[512 + d] * f;
        bb += gb[d] * f;
    }
    G3[j] = g0; G3[256 + j] = g1; G3[512 + j] = g2;
    float b1v = fb1[j] + bb;
    bias2[j] = b1v; bias2[256 + j] = b1v;
}

// ---------------- qv = Qw @ fb2 (256) ----------------
__global__ void qv_k(const float* __restrict__ Qw, const float* __restrict__ fb2,
                     float* __restrict__ qv)
{
    __shared__ float f[256];
    int tid = threadIdx.x;
    f[tid] = fb2[tid];
    __syncthreads();
    float a = 0.f;
    for (int d = 0; d < 256; d++) a += Qw[tid * 256 + d] * f[d];
    qv[tid] = a;
}

// ---------------- init slots / S_p / S_s state ----------------
__global__ void init_k(const float* __restrict__ slots_param, const float* __restrict__ Sp0,
                       const float* __restrict__ Ss0, float* __restrict__ slots,
                       float* __restrict__ Spb, float* __restrict__ Ssb)
{
    int idx = blockIdx.x * 256 + threadIdx.x;
    slots[idx] = slots_param[idx & 2047];
    if (idx < Bc * Sc * 3) {
        int s3 = idx % 24;
        Spb[idx] = Sp0[s3];
        Ssb[idx] = Ss0[s3];
    }
}

// ------- qprep: w2q = LN(slots)@QF ; qc ; invv ; zero accumulators for this iter -------
__global__ __launch_bounds__(256) void qprep2_k(
    const float* __restrict__ slots, const float* __restrict__ norm_g, const float* __restrict__ norm_b,
    const float* __restrict__ QF, const float* __restrict__ qv, const float* __restrict__ Ssb,
    float* __restrict__ w2q, float* __restrict__ qc, float* __restrict__ invv,
    float* __restrict__ denom, float* __restrict__ u1acc,
    float* __restrict__ Spacc, float* __restrict__ Epacc)
{
    int bs = blockIdx.x, tid = threadIdx.x, lane = tid & 63, wave = tid >> 6;
    __shared__ float sl[256];
    __shared__ float redS[4], redS2[4];
    u1acc[bs * 256 + tid] = 0.f;
    if (tid < 3) { Spacc[bs * 3 + tid] = 0.f; Epacc[bs * 3 + tid] = 0.f; }
    if (tid == 0) denom[bs] = 0.f;
    float v = slots[bs * 256 + tid];
    float s = v, s2 = v * v;
    #pragma unroll
    for (int off = 32; off > 0; off >>= 1) { s += __shfl_xor(s, off); s2 += __shfl_xor(s2, off); }
    if (lane == 0) { redS[wave] = s; redS2[wave] = s2; }
    __syncthreads();
    float mean = (redS[0] + redS[1] + redS[2] + redS[3]) * (1.f / 256.f);
    float m2 = (redS2[0] + redS2[1] + redS2[2] + redS2[3]) * (1.f / 256.f);
    float rstd = rsqrtf(m2 - mean * mean + 1e-5f);
    float slv = (v - mean) * rstd * norm_g[tid] + norm_b[tid];
    sl[tid] = slv;
    __syncthreads();
    float wq = 0.f;
    for (int i = 0; i < 256; i++) wq += sl[i] * QF[i * 256 + tid];
    w2q[bs * 256 + tid] = wq;
    float c = slv * qv[tid];
    #pragma unroll
    for (int off = 32; off > 0; off >>= 1) c += __shfl_xor(c, off);
    __syncthreads();
    if (lane == 0) redS[wave] = c;
    __syncthreads();
    if (tid == 0) qc[bs] = redS[0] + redS[1] + redS[2] + redS[3];
    if (tid < 3) invv[bs * 3 + tid] = 1.f / (Ssb[bs * 3 + tid] * 5.0f + EPSc);
}

// ===== fused iteration: dots + softmax(s) + raw-weighted u1/moments/denom accumulation ===
template<bool LAST>
__global__ __launch_bounds__(512) void fused_iter_k(
    const float* __restrict__ AKV, const float* __restrict__ P,
    const float* __restrict__ G3, const float* __restrict__ w2q,
    const float* __restrict__ qc, const float* __restrict__ Spb,
    const float* __restrict__ invv, float* __restrict__ denom,
    float* __restrict__ u1acc, float* __restrict__ Spacc, float* __restrict__ Epacc,
    float* __restrict__ attn_raw)
{
    const int b = blockIdx.y;
    const int tid = threadIdx.x, wave = tid >> 6, lane = tid & 63;
    __shared__ float uls[8][2048];
    __shared__ float dls[8][8];
    __shared__ float mls[8][8][6];

    const float4* G3f = (const float4*)G3;
    float4 g0 = G3f[lane], g1 = G3f[64 + lane], g2 = G3f[128 + lane];
    float4 wq[8];
    float sp0[8], sp1[8], sp2[8], iv0[8], iv1[8], iv2[8], qcr[8];
    #pragma unroll
    for (int s = 0; s < 8; s++) {
        wq[s] = ((const float4*)(w2q + (size_t)(b * 8 + s) * 256))[lane];
        sp0[s] = Spb[(b * 8 + s) * 3 + 0];
        sp1[s] = Spb[(b * 8 + s) * 3 + 1];
        sp2[s] = Spb[(b * 8 + s) * 3 + 2];
        iv0[s] = invv[(b * 8 + s) * 3 + 0];
        iv1[s] = invv[(b * 8 + s) * 3 + 1];
        iv2[s] = invv[(b * 8 + s) * 3 + 2];
        qcr[s] = qc[b * 8 + s];
    }
    float4 au[8];
    #pragma unroll
    for (int s = 0; s < 8; s++) { au[s].x = 0.f; au[s].y = 0.f; au[s].z = 0.f; au[s].w = 0.f; }
    float den[8] = {0.f, 0.f, 0.f, 0.f, 0.f, 0.f, 0.f, 0.f};
    float asp0 = 0.f, asp1 = 0.f, asp2 = 0.f, aep0 = 0.f, aep1 = 0.f, aep2 = 0.f;
    float attv = 0.f;

    const int n0 = blockIdx.x * 64 + wave * 8;
    for (int i = 0; i < 8; i++) {
        size_t base = (size_t)b * Nc_ + (n0 + i);
        const float4 ak = ((const float4*)(AKV + base * 512))[lane];
        const float* pp = P + base * 3;
        float p0 = pp[0], p1 = pp[1], p2 = pp[2];
        float r0s[8], r1s[8], r2s[8], a[8];
        #pragma unroll
        for (int s = 0; s < 8; s++) {
            float r0 = (p0 - sp0[s]) * iv0[s];
            float r1 = (p1 - sp1[s]) * iv1[s];
            float r2 = (p2 - sp2[s]) * iv2[s];
            r0s[s] = r0; r1s[s] = r1; r2s[s] = r2;
            float d0;
            d0  = fmaxf(ak.x + r0 * g0.x + r1 * g1.x + r2 * g2.x, 0.f) * wq[s].x;
            d0 += fmaxf(ak.y + r0 * g0.y + r1 * g1.y + r2 * g2.y, 0.f) * wq[s].y;
            d0 += fmaxf(ak.z + r0 * g0.z + r1 * g1.z + r2 * g2.z, 0.f) * wq[s].z;
            d0 += fmaxf(ak.w + r0 * g0.w + r1 * g1.w + r2 * g2.w, 0.f) * wq[s].w;
            #pragma unroll
            for (int off = 32; off > 0; off >>= 1) d0 += __shfl_xor(d0, off);
            a[s] = (d0 + qcr[s]) * SCALEc;
        }
        float mx = a[0];
        #pragma unroll
        for (int s = 1; s < 8; s++) mx = fmaxf(mx, a[s]);
        float sum = 0.f;
        #pragma unroll
        for (int s = 0; s < 8; s++) { a[s] = __expf(a[s] - mx); sum += a[s]; }
        float inv = 1.f / sum;
        #pragma unroll
        for (int s = 0; s < 8; s++) { a[s] = a[s] * inv + EPSc; den[s] += a[s]; }
        if (LAST) {
            if ((lane & 7) == i) attv = a[lane >> 3];
        } else {
            const float4 av = ((const float4*)(AKV + base * 512 + 256))[lane];
            #pragma unroll
            for (int s = 0; s < 8; s++) {
                float r0 = r0s[s], r1 = r1s[s], r2 = r2s[s], as = a[s];
                au[s].x += as * fmaxf(av.x + r0 * g0.x + r1 * g1.x + r2 * g2.x, 0.f);
                au[s].y += as * fmaxf(av.y + r0 * g0.y + r1 * g1.y + r2 * g2.y, 0.f);
                au[s].z += as * fmaxf(av.z + r0 * g0.z + r1 * g1.z + r2 * g2.z, 0.f);
                au[s].w += as * fmaxf(av.w + r0 * g0.w + r1 * g1.w + r2 * g2.w, 0.f);
            }
            if (lane < 8) {
                float as = a[lane];
                asp0 += as * p0; asp1 += as * p1; asp2 += as * p2;
                aep0 += as * p0 * p0; aep1 += as * p1 * p1; aep2 += as * p2 * p2;
            }
        }
    }
    if (!LAST) {
        #pragma unroll
        for (int s = 0; s < 8; s++)
            *(float4*)&uls[wave][s * 256 + lane * 4] = au[s];
        if (lane < 8) {
            mls[wave][lane][0] = asp0; mls[wave][lane][1] = asp1; mls[wave][lane][2] = asp2;
            mls[wave][lane][3] = aep0; mls[wave][lane][4] = aep1; mls[wave][lane][5] = aep2;
        }
    }
    if (lane == 0) {
        #pragma unroll
        for (int s = 0; s < 8; s++) dls[wave][s] = den[s];
    }
    __syncthreads();
    if (!LAST) {
        for (int idx = tid; idx < 2048; idx += 512) {
            float v = 0.f;
            #pragma unroll
            for (int w2 = 0; w2 < 8; w2++) v += uls[w2][idx];
            atomicAdd(&u1acc[b * 2048 + idx], v);
        }
        if (tid < 48) {
            int s = tid / 6, c = tid % 6;
            float v = 0.f;
            #pragma unroll
            for (int w2 = 0; w2 < 8; w2++) v += mls[w2][s][c];
            if (c < 3) atomicAdd(&Spacc[b * 24 + s * 3 + c], v);
            else       atomicAdd(&Epacc[b * 24 + s * 3 + (c - 3)], v);
        }
    }
    if (tid < 8) {
        float v = 0.f;
        #pragma unroll
        for (int w2 = 0; w2 < 8; w2++) v += dls[w2][tid];
        atomicAdd(&denom[b * 8 + tid], v);
    }
    if (LAST) {
        attn_raw[(size_t)(b * 8 + (lane >> 3)) * Nc_ + n0 + (lane & 7)] = attv;
    }
}

// ------- k_upd: upd = (u1/denom)@fw2 + fb2 ; finalize S_p, S_s (normalized moments) -----
__global__ __launch_bounds__(256) void k_upd(
    const float* __restrict__ u1acc, const float* __restrict__ fw2, const float* __restrict__ fb2,
    const float* __restrict__ Spacc, const float* __restrict__ Epacc, const float* __restrict__ denom,
    float* __restrict__ upd, float* __restrict__ Spb, float* __restrict__ Ssb)
{
    int bs = blockIdx.x, chunk = blockIdx.y;
    int tid = threadIdx.x, c = tid & 31, ks = tid >> 5;
    __shared__ float u1[256];
    __shared__ float part[8][33];
    float idn = 1.f / denom[bs];
    u1[tid] = u1acc[bs * 256 + tid] * idn;
    if (chunk == 0 && tid < 3) {
        float spv = Spacc[bs * 3 + tid] * idn;
        float ep = Epacc[bs * 3 + tid] * idn;
        Spb[bs * 3 + tid] = spv;
        Ssb[bs * 3 + tid] = sqrtf(fmaxf(ep - spv * spv, 0.f) + EPSc);
    }
    __syncthreads();
    int col = (chunk << 5) + c;
    float p = 0.f;
    int j0 = ks << 5;
    for (int j = j0; j < j0 + 32; j++) p += u1[j] * fw2[(size_t)j * 256 + col];
    part[ks][c] = p;
    __syncthreads();
    if (tid < 32) {
        int col2 = (chunk << 5) + tid;
        float a = fb2[col2];
        #pragma unroll
        for (int r = 0; r < 8; r++) a += part[r][tid];
        upd[bs * 256 + col2] = a;
    }
}

// ---------------- GRU gates -> h ----------------
__global__ __launch_bounds__(256) void k_gates(
    const float* __restrict__ upd, const float* __restrict__ slots,
    const float* __restrict__ gwi, const float* __restrict__ gwh,
    const float* __restrict__ gbi, const float* __restrict__ gbh,
    float* __restrict__ hbuf)
{
    int bs = blockIdx.x, chunk = blockIdx.y;
    int tid = threadIdx.x, c = tid & 31, ks = tid >> 5;
    __shared__ float u[256], sp[256];
    __shared__ float part[6][8][33];
    u[tid] = upd[bs * 256 + tid];
    sp[tid] = slots[bs * 256 + tid];
    __syncthreads();
    int col = (chunk << 5) + c;
    float a0 = 0, a1 = 0, a2 = 0, h0 = 0, h1 = 0, h2 = 0;
    int j0 = ks << 5;
    for (int j = j0; j < j0 + 32; j++) {
        const float* wi = gwi + (size_t)j * 768;
        const float* wh = gwh + (size_t)j * 768;
        float uj = u[j], sj = sp[j];
        a0 += uj * wi[col]; a1 += uj * wi[col + 256]; a2 += uj * wi[col + 512];
        h0 += sj * wh[col]; h1 += sj * wh[col + 256]; h2 += sj * wh[col + 512];
    }
    part[0][ks][c] = a0; part[1][ks][c] = a1; part[2][ks][c] = a2;
    part[3][ks][c] = h0; part[4][ks][c] = h1; part[5][ks][c] = h2;
    __syncthreads();
    if (tid < 32) {
        int col2 = (chunk << 5) + tid;
        float gx0 = gbi[col2], gx1 = gbi[col2 + 256], gx2 = gbi[col2 + 512];
        float gh0 = gbh[col2], gh1 = gbh[col2 + 256], gh2 = gbh[col2 + 512];
        #pragma unroll
        for (int r = 0; r < 8; r++) {
            gx0 += part[0][r][tid]; gx1 += part[1][r][tid]; gx2 += part[2][r][tid];
            gh0 += part[3][r][tid]; gh1 += part[4][r][tid]; gh2 += part[5][r][tid];
        }
        float rg = 1.f / (1.f + expf(-(gx0 + gh0)));
        float zg = 1.f / (1.f + expf(-(gx1 + gh1)));
        float ng = tanhf(gx2 + rg * gh2);
        hbuf[bs * 256 + col2] = (1.f - zg) * ng + zg * sp[col2];
    }
}

// ---------------- mlp1: t1 = relu(LN(h)@w1 + b1) ----------------
__global__ __launch_bounds__(256) void k_mlp1(
    const float* __restrict__ hbuf, const float* __restrict__ lng, const float* __restrict__ lnb,
    const float* __restrict__ w1, const float* __restrict__ b1, float* __restrict__ t1)
{
    int bs = blockIdx.x, chunk = blockIdx.y;
    int tid = threadIdx.x, lane = tid & 63, wave = tid >> 6;
    int c = tid & 31, ks = tid >> 5;
    __shared__ float y0[256];
    __shared__ float part[8][33];
    __shared__ float rs[4], rs2[4];
    float h = hbuf[bs * 256 + tid];
    float s = h, s2 = h * h;
    #pragma unroll
    for (int off = 32; off > 0; off >>= 1) { s += __shfl_xor(s, off); s2 += __shfl_xor(s2, off); }
    if (lane == 0) { rs[wave] = s; rs2[wave] = s2; }
    __syncthreads();
    float mean = (rs[0] + rs[1] + rs[2] + rs[3]) * (1.f / 256.f);
    float m2 = (rs2[0] + rs2[1] + rs2[2] + rs2[3]) * (1.f / 256.f);
    float rstd = rsqrtf(m2 - mean * mean + 1e-5f);
    y0[tid] = (h - mean) * rstd * lng[tid] + lnb[tid];
    __syncthreads();
    int col = (chunk << 5) + c;
    float p = 0.f;
    int j0 = ks << 5;
    for (int j = j0; j < j0 + 32; j++) p += y0[j] * w1[(size_t)j * 1024 + col];
    part[ks][c] = p;
    __syncthreads();
    if (tid < 32) {
        int col2 = (chunk << 5) + tid;
        float a = b1[col2];
        #pragma unroll
        for (int r = 0; r < 8; r++) a += part[r][tid];
        t1[bs * 1024 + col2] = fmaxf(a, 0.f);
    }
}

// ---------------- mlp2: slots = h + t1@w2 + b2 ----------------
__global__ __launch_bounds__(256) void k_mlp2(
    const float* __restrict__ t1, const float* __restrict__ hbuf,
    const float* __restrict__ w2, const float* __restrict__ b2, float* __restrict__ slots)
{
    int bs = blockIdx.x, chunk = blockIdx.y;
    int tid = threadIdx.x, c = tid & 31, ks = tid >> 5;
    __shared__ float t1s[1024];
    __shared__ float part[8][33];
    for (int i = tid; i < 1024; i += 256) t1s[i] = t1[bs * 1024 + i];
    __syncthreads();
    int col = (chunk << 5) + c;
    float p = 0.f;
    int j0 = ks << 7;
    for (int j = j0; j < j0 + 128; j++) p += t1s[j] * w2[(size_t)j * 256 + col];
    part[ks][c] = p;
    __syncthreads();
    if (tid < 32) {
        int col2 = (chunk << 5) + tid;
        float a = b2[col2] + hbuf[bs * 256 + col2];
        #pragma unroll
        for (int r = 0; r < 8; r++) a += part[r][tid];
        slots[bs * 256 + col2] = a;
    }
}

// ---------------- attn output (normalized) ----------------
__global__ void attn_out_k(const float* __restrict__ attn_raw, const float* __restrict__ denom,
                           float* __restrict__ out_attn)
{
    int b = blockIdx.y;
    int idx = blockIdx.x * 256 + threadIdx.x;
    int s = idx >> 12;
    out_attn[(size_t)b * Sc * Nc_ + idx] = attn_raw[(size_t)b * Sc * Nc_ + idx] / denom[b * 8 + s];
}

// ---------------- out = slots@fin_w + fin_b ----------------
__global__ void out_k(const float* __restrict__ slots, const float* __restrict__ fin_w,
                      const float* __restrict__ fin_b, float* __restrict__ outp)
{
    int bs = blockIdx.x;
    int tid = threadIdx.x;
    __shared__ float sl[256];
    sl[tid] = slots[bs * 256 + tid];
    __syncthreads();
    float acc = fin_b[tid];
    for (int j = 0; j < 256; j++) acc += sl[j] * fin_w[j * 256 + tid];
    outp[bs * 256 + tid] = acc;
}

extern "C" void kernel_launch(void* const* d_in, const int* in_sizes, int n_in,
                              void* d_out, int out_size, void* d_ws, size_t ws_size,
                              hipStream_t stream)
{
    const float* inputs       = (const float*)d_in[0];
    const float* point_coords = (const float*)d_in[1];
    const float* slots_param  = (const float*)d_in[2];
    const float* Sp0          = (const float*)d_in[3];
    const float* Ss0          = (const float*)d_in[4];
    const float* Qw           = (const float*)d_in[5];
    const float* Kw           = (const float*)d_in[6];
    const float* Vw           = (const float*)d_in[7];
    const float* norm_g       = (const float*)d_in[8];
    const float* norm_b       = (const float*)d_in[9];
    const float* gw           = (const float*)d_in[10];
    const float* gb           = (const float*)d_in[11];
    const float* fw1          = (const float*)d_in[12];
    const float* fb1          = (const float*)d_in[13];
    const float* fw2          = (const float*)d_in[14];
    const float* fb2          = (const float*)d_in[15];
    const float* gru_wi       = (const float*)d_in[16];
    const float* gru_wh       = (const float*)d_in[17];
    const float* gru_bi       = (const float*)d_in[18];
    const float* gru_bh       = (const float*)d_in[19];
    const float* mlp_ln_g     = (const float*)d_in[20];
    const float* mlp_ln_b     = (const float*)d_in[21];
    const float* mlp_w1       = (const float*)d_in[22];
    const float* mlp_b1       = (const float*)d_in[23];
    const float* mlp_w2       = (const float*)d_in[24];
    const float* mlp_b2       = (const float*)d_in[25];
    const float* im_ln1_g     = (const float*)d_in[26];
    const float* im_ln1_b     = (const float*)d_in[27];
    const float* im_w1        = (const float*)d_in[28];
    const float* im_b1        = (const float*)d_in[29];
    const float* im_w2        = (const float*)d_in[30];
    const float* im_b2        = (const float*)d_in[31];
    const float* im_ln2_g     = (const float*)d_in[32];
    const float* im_ln2_b     = (const float*)d_in[33];
    const float* fin_w        = (const float*)d_in[34];
    const float* fin_b        = (const float*)d_in[35];

    float* W = (float*)d_ws;
    float* AKV    = W;                        // 8,388,608 f32
    u16*   Abf    = (u16*)(W);                // 8192x768 bf16 (aliases AKV, dead by gemm3)
    u16*   h1bf   = (u16*)(W + 3145728);      // 8192x768 bf16 (aliases AKV)
    float* x2     = W + 8388608;              // 16384x256 f32
    u16*   x2bf   = (u16*)(W + 12582912);     // 16384x256 bf16
    float* KVF    = W + 14680064;             // 131072
    u16*   KVFbt  = (u16*)(W + 14811136);     // 65536 slots
    u16*   W1bt   = (u16*)(W + 14876672);     // 294912 slots
    u16*   W2bt   = (u16*)(W + 15171584);     // 98304 slots
    u16*   Qwbf   = (u16*)(W + 15269888);     // 32768 slots
    u16*   fw2bf  = (u16*)(W + 15302656);     // 32768 slots
    float* QF     = W + 15335424;             // 65536
    float* qv     = W + 15400960;             // 256
    float* G3     = W + 15401216;             // 768
    float* bias2  = W + 15401984;             // 512
    float* slots  = W + 15402496;             // 8192
    float* Spb    = W + 15410688;             // 96
    float* Ssb    = W + 15410784;             // 96
    float* w2q    = W + 15410880;             // 8192
    float* qcb    = W + 15419072;             // 32
    float* invv   = W + 15419104;             // 96
    float* attn_raw = W + 15419200;           // 131072
    float* denom  = W + 15550272;             // 32
    float* u1acc  = W + 15550304;             // 8192
    float* Spacc  = W + 15558496;             // 96
    float* Epacc  = W + 15558592;             // 96
    float* updb   = W + 15558688;             // 8192
    float* hbuf   = W + 15566880;             // 8192
    float* t1buf  = W + 15575072;             // 32768  -- end 15,607,840 f (~62.4 MB)

    // ---- one-time precompute ----
    kvf_k<<<256, 512, 0, stream>>>(Kw, Vw, fw1, KVF);
    g3b_k<<<1, 256, 0, stream>>>(gw, gb, fb1, fw1, G3, bias2);
    init_k<<<32, 256, 0, stream>>>(slots_param, Sp0, Ss0, slots, Spb, Ssb);
    qv_k<<<1, 256, 0, stream>>>(Qw, fb2, qv);
    cvt_k<<<256, 256, 0, stream>>>(Qw, Qwbf);
    cvt_k<<<256, 256, 0, stream>>>(fw2, fw2bf);
    tcvt_k<<<dim3(24, 24), 256, 0, stream>>>(im_w1, W1bt, 768, 768);
    tcvt_k<<<dim3(8, 24), 256, 0, stream>>>(im_w2, W2bt, 768, 256);
    tcvt_k<<<dim3(16, 8), 256, 0, stream>>>(KVF, KVFbt, 256, 512);
    mfma_gemm<false, false><<<dim3(2, 2), 256, 0, stream>>>(Qwbf, fw2bf, nullptr, QF, 256, 256, 256);

    // ---- input MLP (bf16 MFMA, 2 chunks of 8192 rows) ----
    for (int ch = 0; ch < 2; ch++) {
        const float* Xc = inputs + (size_t)ch * 8192 * DINc;
        lncvt_k<<<8192, 256, 0, stream>>>(Xc, im_ln1_g, im_ln1_b, Abf, DINc);
        mfma_gemm<true, true><<<dim3(6, 64), 256, 0, stream>>>(Abf, W1bt, im_b1, h1bf, 8192, 768, 768);
        mfma_gemm<false, false><<<dim3(2, 64), 256, 0, stream>>>(h1bf, W2bt, im_b2,
            x2 + (size_t)ch * 8192 * Dc, 8192, 256, 768);
    }
    lncvt_k<<<16384, 256, 0, stream>>>(x2, im_ln2_g, im_ln2_b, x2bf, 256);
    mfma_gemm<false, false><<<dim3(4, 128), 256, 0, stream>>>(x2bf, KVFbt, bias2, AKV, 16384, 512, 256);

    float* out_slots = (float*)d_out;
    float* out_attn  = (float*)d_out + Bc * Sc * Dc;

    // ---- iteration loop ----
    for (int t = 0; t <= 3; t++) {
        qprep2_k<<<32, 256, 0, stream>>>(slots, norm_g, norm_b, QF, qv, Ssb,
                                         w2q, qcb, invv, denom, u1acc, Spacc, Epacc);
        if (t < 3) {
            fused_iter_k<false><<<dim3(64, 4), 512, 0, stream>>>(
                AKV, point_coords, G3, w2q, qcb, Spb, invv,
                denom, u1acc, Spacc, Epacc, nullptr);
            k_upd<<<dim3(32, 8), 256, 0, stream>>>(u1acc, fw2, fb2, Spacc, Epacc, denom,
                                                   updb, Spb, Ssb);
            k_gates<<<dim3(32, 8), 256, 0, stream>>>(updb, slots, gru_wi, gru_wh, gru_bi, gru_bh, hbuf);
            k_mlp1<<<dim3(32, 32), 256, 0, stream>>>(hbuf, mlp_ln_g, mlp_ln_b, mlp_w1, mlp_b1, t1buf);
            k_mlp2<<<dim3(32, 8), 256, 0, stream>>>(t1buf, hbuf, mlp_w2, mlp_b2, slots);
        } else {
            fused_iter_k<true><<<dim3(64, 4), 512, 0, stream>>>(
                AKV, point_coords, G3, w2q, qcb, Spb, invv,
                denom, u1acc, Spacc, Epacc, attn_raw);
            attn_out_k<<<dim3(128, 4), 256, 0, stream>>>(attn_raw, denom, out_attn);
            out_k<<<32, 256, 0, stream>>>(slots, fin_w, fin_b, out_slots);
        }
    }
}